// Round 1
// baseline (133.721 us; speedup 1.0000x reference)
//
#include <hip/hip_runtime.h>

// Multi-scale gradient-difference loss, restructured as line-parallel
// reductions (rows / columns / diagonals), nothing materialized.
//
// scales s = 1,4,...,199 (67 scales); dirs (0,s),(s,0),(s,s); layers 3.
// Both taps of each dir live on one 1-D line -> stage line in LDS, loop scales.

#define NSCALES 67
#define IMG_H 256
#define IMG_W 256
#define NPIX 65536
#define NLINES 2046          // 512 rows (H) + 512 cols (V) + 1022 diagonals (D)
#define ROI_BLOCKS 8

// d_ws layout in doubles:
#define P1_OFF 0                           // NLINES*4 : per-line {S1,S2,posCnt,sumAbsPrd}
#define ROIP_OFF (NLINES * 4)              // 8 roi-sum partials
#define P2_OFF (ROIP_OFF + ROI_BLOCKS)     // NLINES  : per-line t1 partial
#define MISC_OFF (P2_OFF + NLINES)         // c[2], invC[2], term23[2]

__device__ __forceinline__ double wave_red(double v) {
#pragma unroll
  for (int o = 32; o > 0; o >>= 1) v += __shfl_down(v, o, 64);
  return v;
}

// line id -> (batch, flat base index, stride, length)
__device__ __forceinline__ void decode_line(int id, int& b, int& base, int& stride, int& L) {
  if (id < 512) {                      // horizontal: row y, taps (y, x) & (y, x+s)
    b = id >> 8; int y = id & 255;
    base = y * IMG_W; stride = 1; L = IMG_W;
  } else if (id < 1024) {              // vertical: column x
    int t = id - 512; b = t >> 8;
    base = t & 255; stride = IMG_W; L = IMG_H;
  } else {                             // diagonal c = x - y in [-255,255]
    int t = id - 1024; b = (t >= 511) ? 1 : 0;
    int d = t - b * 511; int c = d - 255;
    int ac = (c < 0) ? -c : c;
    base = (c < 0) ? (-c) * IMG_W : c;
    stride = IMG_W + 1; L = 256 - ac;
  }
}

extern "C" __global__ void __launch_bounds__(256) pass1_kernel(
    const float* __restrict__ Pred, const float* __restrict__ GT,
    const float* __restrict__ ROI, double* __restrict__ ws) {
  __shared__ float lR[256];
  __shared__ float lP[3][256];
  __shared__ float lG[3][256];
  __shared__ double red[4][4];
  const int id = blockIdx.x;
  const int tid = threadIdx.x;
  const int wid = tid >> 6, lane = tid & 63;

  if (id >= NLINES) {                  // trailing blocks: ROI mask sum per image
    int j = id - NLINES;               // 0..7
    int b = j >> 2, seg = j & 3;
    const float* R = ROI + b * NPIX;
    float s = 0.f;
    int lo = seg * 16384, hi = lo + 16384;
    for (int i = lo + tid; i < hi; i += 256) s += R[i];
    double sd = wave_red((double)s);
    if (lane == 0) red[wid][0] = sd;
    __syncthreads();
    if (tid == 0) ws[ROIP_OFF + j] = red[0][0] + red[1][0] + red[2][0] + red[3][0];
    return;
  }

  int b, base, stride, L;
  decode_line(id, b, base, stride, L);
  const float* P = Pred + b * (3 * NPIX);
  const float* G = GT + b * (3 * NPIX);
  const float* R = ROI + b * NPIX;
  for (int i = tid; i < L; i += 256) {
    int a = base + i * stride;
    lR[i] = R[a];
    lP[0][i] = P[a]; lP[1][i] = P[a + NPIX]; lP[2][i] = P[a + 2 * NPIX];
    lG[0][i] = G[a]; lG[1][i] = G[a + NPIX]; lG[2][i] = G[a + 2 * NPIX];
  }
  __syncthreads();

  double s1 = 0, s2 = 0, pc = 0, sp = 0;
  for (int k = wid; k < NSCALES; k += 4) {    // 4 waves split the scales
    int s = 1 + 3 * k;
    int n = L - s;
    float f1 = 0.f, f2 = 0.f, fc = 0.f, fp = 0.f;   // short f32 runs (<=12 adds)
    for (int i = lane; i < n; i += 64) {
      float r = lR[i] * lR[i + s];            // 0 or 1
#pragma unroll
      for (int l = 0; l < 3; ++l) {
        float dP = r * (lP[l][i] - lP[l][i + s]);
        float dG = r * (lG[l][i] - lG[l][i + s]);
        float q = dP * __builtin_amdgcn_rcpf(dG + 1e-5f);  // sign-exact approx div
        float aG = fabsf(dG);
        if (q > 0.f) { f1 += aG * q; f2 += aG; }  // S1 += |dG|*relu(q); S2 += |dG|*(relu(q)>0)
        if (dG > 0.f) fc += 1.f;                  // pos_cnt
        fp += fabsf(dP);                          // sum |difPrd|
      }
    }
    s1 += (double)f1; s2 += (double)f2; pc += (double)fc; sp += (double)fp;
  }
  s1 = wave_red(s1); s2 = wave_red(s2); pc = wave_red(pc); sp = wave_red(sp);
  if (lane == 0) { red[wid][0] = s1; red[wid][1] = s2; red[wid][2] = pc; red[wid][3] = sp; }
  __syncthreads();
  if (tid < 4)
    ws[P1_OFF + id * 4 + tid] = red[0][tid] + red[1][tid] + red[2][tid] + red[3][tid];
}

extern "C" __global__ void __launch_bounds__(64) mid_kernel(
    double* __restrict__ ws, float* __restrict__ out) {
  const int lane = threadIdx.x;
  double a0[4] = {0, 0, 0, 0}, a1[4] = {0, 0, 0, 0};
  for (int p = lane; p < NLINES; p += 64) {
    int b, base, stride, L; decode_line(p, b, base, stride, L);
    double v0 = ws[P1_OFF + p * 4 + 0], v1 = ws[P1_OFF + p * 4 + 1];
    double v2 = ws[P1_OFF + p * 4 + 2], v3 = ws[P1_OFF + p * 4 + 3];
    if (b) { a1[0] += v0; a1[1] += v1; a1[2] += v2; a1[3] += v3; }
    else   { a0[0] += v0; a0[1] += v1; a0[2] += v2; a0[3] += v3; }
  }
  double r0 = 0, r1 = 0;
  if (lane < ROI_BLOCKS) {
    double v = ws[ROIP_OFF + lane];
    if (lane < 4) r0 = v; else r1 = v;
  }
#pragma unroll
  for (int j = 0; j < 4; ++j) { a0[j] = wave_red(a0[j]); a1[j] = wave_red(a1[j]); }
  r0 = wave_red(r0); r1 = wave_red(r1);
  if (lane == 0) {
    double S1[2] = {a0[0], a1[0]}, S2[2] = {a0[1], a1[1]};
    double PC[2] = {a0[2], a1[2]}, SP[2] = {a0[3], a1[3]};
    double RS[2] = {r0, r1};
    for (int b = 0; b < 2; ++b) {
      float c = (float)(S1[b] / (S2[b] + 1e-4));
      out[1 + b] = c;                                   // NormConst
      float meanPrd = (float)(SP[b] / PC[b]);
      bool big = RS[b] > 200.0;
      float term2 = (big && meanPrd > 30.f && c > 10.f) ? (meanPrd - 30.f) : 0.f;
      float fact = 0.1f / (c + 0.001f);
      float term3 = (big && meanPrd < 2.f && c < 0.1f) ? (0.2f - meanPrd) * fact : 0.f;
      ws[MISC_OFF + b] = (double)c;
      ws[MISC_OFF + 2 + b] = (c > 1e-4f) ? (1.0 / (double)c) : 1.0;
      ws[MISC_OFF + 4 + b] = (double)(term2 + term3);
    }
  }
}

extern "C" __global__ void __launch_bounds__(256) pass2_kernel(
    const float* __restrict__ Pred, const float* __restrict__ GT,
    const float* __restrict__ ROI, double* __restrict__ ws) {
  __shared__ float lR[256];
  __shared__ float lP[3][256];
  __shared__ float lG[3][256];
  __shared__ double red[4];
  const int id = blockIdx.x;
  const int tid = threadIdx.x;
  const int wid = tid >> 6, lane = tid & 63;

  int b, base, stride, L;
  decode_line(id, b, base, stride, L);
  const float invC = (float)ws[MISC_OFF + 2 + b];
  const float* P = Pred + b * (3 * NPIX);
  const float* G = GT + b * (3 * NPIX);
  const float* R = ROI + b * NPIX;
  for (int i = tid; i < L; i += 256) {
    int a = base + i * stride;
    lR[i] = R[a];
    lP[0][i] = P[a]; lP[1][i] = P[a + NPIX]; lP[2][i] = P[a + 2 * NPIX];
    lG[0][i] = G[a]; lG[1][i] = G[a + NPIX]; lG[2][i] = G[a + 2 * NPIX];
  }
  __syncthreads();

  double t = 0;
  for (int k = wid; k < NSCALES; k += 4) {
    int s = 1 + 3 * k;
    int n = L - s;
    float f = 0.f;
    for (int i = lane; i < n; i += 64) {
      float r = lR[i] * lR[i + s];
#pragma unroll
      for (int l = 0; l < 3; ++l) {
        float dP = r * (lP[l][i] - lP[l][i + s]);
        float dG = r * (lG[l][i] - lG[l][i + s]);
        f += fabsf(dG - dP * invC);
      }
    }
    t += (double)f;
  }
  t = wave_red(t);
  if (lane == 0) red[wid] = t;
  __syncthreads();
  if (tid == 0) ws[P2_OFF + id] = red[0] + red[1] + red[2] + red[3];
}

extern "C" __global__ void __launch_bounds__(64) final_kernel(
    const double* __restrict__ ws, float* __restrict__ out) {
  const int lane = threadIdx.x;
  double t0 = 0, t1 = 0;
  for (int p = lane; p < NLINES; p += 64) {
    int b, base, stride, L; decode_line(p, b, base, stride, L);
    double v = ws[P2_OFF + p];
    if (b) t1 += v; else t0 += v;
  }
  t0 = wave_red(t0); t1 = wave_red(t1);
  if (lane == 0) {
    double T[2] = {t0, t1};
    double loss = 0;
    for (int b = 0; b < 2; ++b) {
      double c = ws[MISC_OFF + b];
      // term1 = mean over 603*65536 elements (zeros included), gated on c
      double term1 = (c > 1e-4) ? T[b] / (603.0 * 65536.0) : 0.0;
      loss += term1 + ws[MISC_OFF + 4 + b];
    }
    out[0] = (float)loss;
  }
}

extern "C" void kernel_launch(void* const* d_in, const int* in_sizes, int n_in,
                              void* d_out, int out_size, void* d_ws, size_t ws_size,
                              hipStream_t stream) {
  (void)in_sizes; (void)n_in; (void)out_size; (void)ws_size;
  const float* Pred = (const float*)d_in[0];
  const float* GT = (const float*)d_in[1];
  const float* ROI = (const float*)d_in[2];
  float* out = (float*)d_out;
  double* ws = (double*)d_ws;   // needs ~82 KB

  hipLaunchKernelGGL(pass1_kernel, dim3(NLINES + ROI_BLOCKS), dim3(256), 0, stream,
                     Pred, GT, ROI, ws);
  hipLaunchKernelGGL(mid_kernel, dim3(1), dim3(64), 0, stream, ws, out);
  hipLaunchKernelGGL(pass2_kernel, dim3(NLINES), dim3(256), 0, stream,
                     Pred, GT, ROI, ws);
  hipLaunchKernelGGL(final_kernel, dim3(1), dim3(64), 0, stream, ws, out);
}